// Round 4
// baseline (753.432 us; speedup 1.0000x reference)
//
#include <hip/hip_runtime.h>
#include <stdint.h>

typedef __bf16 bf16x8 __attribute__((ext_vector_type(8)));
typedef float  f32x4  __attribute__((ext_vector_type(4)));

// ---------------- gather / copy (fp32 rows, uint4 = 4 floats) ----------------
__global__ void k_unpool(const uint4* __restrict__ xin, const int* __restrict__ up,
                         uint4* __restrict__ xout, int N, int rowU4) {
  int i = blockIdx.x * 256 + threadIdx.x;
  if (i >= N * rowU4) return;
  int n = i / rowU4, j = i - n * rowU4;
  xout[i] = xin[(size_t)up[n] * rowU4 + j];
}

__global__ void k_skip(const uint4* __restrict__ skip, uint4* __restrict__ xcat,
                       int N, int rowU4, int dstStrideU4, int dstOffU4) {
  int i = blockIdx.x * 256 + threadIdx.x;
  if (i >= N * rowU4) return;
  int n = i / rowU4, j = i - n * rowU4;
  xcat[(size_t)n * dstStrideU4 + dstOffU4 + j] = skip[i];
}

// ---------------- CSR build (hist + hierarchical scan + place) ----------------
__global__ void k_hist(const int* __restrict__ dst, int E, int* __restrict__ cnt) {
  int e = blockIdx.x * 256 + threadIdx.x;
  if (e < E) atomicAdd(&cnt[dst[e]], 1);
}

__global__ void k_blocksum(const int* __restrict__ cnt, int N, int* __restrict__ bsum) {
  int b = blockIdx.x;
  int t = threadIdx.x;
  int i0 = b * 1024 + t * 4;
  int s = 0;
  if (i0 + 3 < N) {
    int4 v = *reinterpret_cast<const int4*>(cnt + i0);
    s = v.x + v.y + v.z + v.w;
  } else {
    #pragma unroll
    for (int k = 0; k < 4; ++k) if (i0 + k < N) s += cnt[i0 + k];
  }
  #pragma unroll
  for (int o = 32; o > 0; o >>= 1) s += __shfl_down(s, o, 64);
  __shared__ int ws[4];
  if ((t & 63) == 0) ws[t >> 6] = s;
  __syncthreads();
  if (t == 0) bsum[b] = ws[0] + ws[1] + ws[2] + ws[3];
}

__global__ void k_scanb(int* __restrict__ bsum, int nb) {
  __shared__ int wsum[16];
  int t = threadIdx.x, lane = t & 63, w = t >> 6;
  int v = (t < nb) ? bsum[t] : 0;
  int x = v;
  #pragma unroll
  for (int o = 1; o < 64; o <<= 1) { int y = __shfl_up(x, o, 64); if (lane >= o) x += y; }
  if (lane == 63) wsum[w] = x;
  __syncthreads();
  int wpre = 0;
  #pragma unroll
  for (int k = 0; k < 16; ++k) if (k < w) wpre += wsum[k];
  int excl = wpre + x - v;
  if (t < nb) bsum[t] = excl;
}

__global__ void k_offsets(const int* __restrict__ cnt, int N, const int* __restrict__ bsum,
                          int* __restrict__ off, int E) {
  int b = blockIdx.x;
  int t = threadIdx.x, lane = t & 63, w = t >> 6;
  int i0 = b * 1024 + t * 4;
  int v0 = 0, v1 = 0, v2 = 0, v3 = 0;
  if (i0 + 3 < N) {
    int4 v = *reinterpret_cast<const int4*>(cnt + i0);
    v0 = v.x; v1 = v.y; v2 = v.z; v3 = v.w;
  } else {
    if (i0 + 0 < N) v0 = cnt[i0 + 0];
    if (i0 + 1 < N) v1 = cnt[i0 + 1];
    if (i0 + 2 < N) v2 = cnt[i0 + 2];
    if (i0 + 3 < N) v3 = cnt[i0 + 3];
  }
  int s = v0 + v1 + v2 + v3, x = s;
  #pragma unroll
  for (int o = 1; o < 64; o <<= 1) { int y = __shfl_up(x, o, 64); if (lane >= o) x += y; }
  __shared__ int ws[4];
  if (lane == 63) ws[w] = x;
  __syncthreads();
  int wpre = 0;
  #pragma unroll
  for (int k = 0; k < 4; ++k) if (k < w) wpre += ws[k];
  int excl = bsum[b] + wpre + x - s;
  if (i0 + 0 < N) off[i0 + 0] = excl; excl += v0;
  if (i0 + 1 < N) off[i0 + 1] = excl; excl += v1;
  if (i0 + 2 < N) off[i0 + 2] = excl; excl += v2;
  if (i0 + 3 < N) off[i0 + 3] = excl;
  if (b == 0 && t == 0) off[N] = E;
}

__global__ void k_place(const int* __restrict__ dst, int E, const int* __restrict__ off,
                        int* __restrict__ cur, int* __restrict__ eid) {
  int e = blockIdx.x * 256 + threadIdx.x;
  if (e >= E) return;
  int d = dst[e];
  int p = atomicAdd(&cur[d], 1);
  eid[off[d] + p] = e;
}

// ---------------- weight pre-pack (fp32 W,R -> bf16 MFMA B-fragments) ----------------
template<int Cin, int Cout>
__global__ void k_pack(const float* __restrict__ W, const float* __restrict__ R,
                       __bf16* __restrict__ Bp) {
  constexpr int NC = 10 * Cout;
  constexpr int CT = NC / 16;
  constexpr int KP = (Cin + 31) & ~31;
  int o = blockIdx.x * 256 + threadIdx.x;
  if (o >= KP * NC) return;
  int j = o & 7;
  int lane = (o >> 3) & 63;
  int tile = o >> 9;
  int ct = tile % CT, kc = tile / CT;
  int kg = kc * 32 + ((lane >> 4) * 8) + j;
  int col = ct * 16 + (lane & 15);
  float v = 0.f;
  if (kg < Cin) {
    if (col < 9 * Cout) {
      int k9 = col / Cout, cout = col - k9 * Cout;
      v = W[(k9 * Cin + kg) * Cout + cout];
    } else {
      v = R[kg * Cout + (col - 9 * Cout)];
    }
  }
  Bp[o] = (__bf16)v;
}

// ---------------- Z = X @ B  (MFMA 16x16x32 bf16, fp32 A converted on the fly) --------
template<int Cin, int NC>
__global__ __launch_bounds__(256) void k_zgemm(const float* __restrict__ X,
                        const __bf16* __restrict__ Bp, __bf16* __restrict__ Z, int N) {
  constexpr int KP = (Cin + 31) & ~31;
  constexpr int KC = KP / 32;
  constexpr int CT = NC / 16;
  int lane = threadIdx.x & 63;
  int wave = threadIdx.x >> 6;
  int n0 = blockIdx.x * 64 + wave * 16;
  if (n0 >= N) return;
  int c15 = lane & 15, q = lane >> 4;

  bf16x8 a[KC];
  #pragma unroll
  for (int kc = 0; kc < KC; ++kc) {
    int kofs = kc * 32 + q * 8;
    if (kofs + 8 <= Cin) {
      const float* xr = X + (size_t)(n0 + c15) * Cin + kofs;
      f32x4 lo = *reinterpret_cast<const f32x4*>(xr);
      f32x4 hi = *reinterpret_cast<const f32x4*>(xr + 4);
      #pragma unroll
      for (int t = 0; t < 4; ++t) { a[kc][t] = (__bf16)lo[t]; a[kc][4 + t] = (__bf16)hi[t]; }
    } else {
      #pragma unroll
      for (int t = 0; t < 8; ++t) a[kc][t] = (__bf16)0.0f;
    }
  }

  for (int ct = 0; ct < CT; ++ct) {
    f32x4 acc = {0.f, 0.f, 0.f, 0.f};
    #pragma unroll
    for (int kc = 0; kc < KC; ++kc) {
      bf16x8 b = *reinterpret_cast<const bf16x8*>(Bp + ((size_t)(kc * CT + ct) * 64 + lane) * 8);
      acc = __builtin_amdgcn_mfma_f32_16x16x32_bf16(a[kc], b, acc, 0, 0, 0);
    }
    __bf16* zb = Z + (size_t)n0 * NC + ct * 16 + c15;
    #pragma unroll
    for (int r = 0; r < 4; ++r) {
      zb[(size_t)(q * 4 + r) * NC] = (__bf16)acc[r];
    }
  }
}

// ------------- edge aggregation: each lane owns 8 channels, b128 Z loads -------------
template<int Cout>
__global__ __launch_bounds__(256) void k_econv(const int* __restrict__ src,
                        const float* __restrict__ pseudo,
                        const int* __restrict__ off, const int* __restrict__ eid,
                        const __bf16* __restrict__ Z,
                        const float* __restrict__ bias,
                        float* __restrict__ out, int N, int outStride) {
  constexpr int NC = 10 * Cout;
  constexpr int LPD = Cout / 8;   // lanes per dst
  int t = blockIdx.x * 256 + threadIdx.x;
  int d = t / LPD;
  int sub = t % LPD;
  if (d >= N) return;
  int cbase = sub * 8;

  float acc[8];
  {
    // own-node R-term folded into Z as columns [9*Cout, 10*Cout)
    bf16x8 r = *reinterpret_cast<const bf16x8*>(Z + (size_t)d * NC + 9 * Cout + cbase);
    #pragma unroll
    for (int v = 0; v < 8; ++v) acc[v] = (float)r[v];
  }

  int b0 = off[d], b1 = off[d + 1];
  for (int i = b0; i < b1; ++i) {
    int e = eid[i];
    int s = src[e];
    float2 ps = *reinterpret_cast<const float2*>(pseudo + 2 * (size_t)e);
    const __bf16* zr = Z + (size_t)s * NC + cbase;
    bf16x8 zf[9];
    #pragma unroll
    for (int k = 0; k < 9; ++k)
      zf[k] = *reinterpret_cast<const bf16x8*>(zr + k * Cout);
    float t0 = ps.x, t1 = ps.y;
    float u0 = 1.f - t0;
    float wi[3] = {0.5f * u0 * u0, -t0 * t0 + t0 + 0.5f, 0.5f * t0 * t0};
    float u1 = 1.f - t1;
    float wj[3] = {0.5f * u1 * u1, -t1 * t1 + t1 + 0.5f, 0.5f * t1 * t1};
    #pragma unroll
    for (int ki = 0; ki < 3; ++ki)
      #pragma unroll
      for (int kj = 0; kj < 3; ++kj) {
        float w = wi[ki] * wj[kj];
        #pragma unroll
        for (int v = 0; v < 8; ++v)
          acc[v] += w * (float)zf[ki * 3 + kj][v];
      }
  }

  #pragma unroll
  for (int v = 0; v < 8; ++v) acc[v] = fmaxf(acc[v] + bias[cbase + v], 0.f);

  float* op = out + (size_t)d * outStride + cbase;
  f32x4 o0 = {acc[0], acc[1], acc[2], acc[3]};
  f32x4 o1 = {acc[4], acc[5], acc[6], acc[7]};
  *reinterpret_cast<f32x4*>(op) = o0;
  *reinterpret_cast<f32x4*>(op + 4) = o1;
}

extern "C" void kernel_launch(void* const* d_in, const int* in_sizes, int n_in,
                              void* d_out, int out_size, void* d_ws, size_t ws_size,
                              hipStream_t stream) {
  const float* x0      = (const float*)d_in[0];
  const int*   up1     = (const int*)d_in[1];
  const int*   edge1   = (const int*)d_in[2];
  const float* pseudo1 = (const float*)d_in[3];
  const float* skip1   = (const float*)d_in[4];
  const int*   up2     = (const int*)d_in[5];
  const int*   edge2   = (const int*)d_in[6];
  const float* pseudo2 = (const float*)d_in[7];
  const float* skip2   = (const float*)d_in[8];
  const float* W1a = (const float*)d_in[9];
  const float* R1a = (const float*)d_in[10];
  const float* b1a = (const float*)d_in[11];
  const float* W2a = (const float*)d_in[12];
  const float* R2a = (const float*)d_in[13];
  const float* b2a = (const float*)d_in[14];
  const float* W1b = (const float*)d_in[15];
  const float* R1b = (const float*)d_in[16];
  const float* b1b = (const float*)d_in[17];
  const float* W2b = (const float*)d_in[18];
  const float* R2b = (const float*)d_in[19];
  const float* b2b = (const float*)d_in[20];

  const int N1 = 40000, N2 = 160000, E1 = 240000, E2 = 960000;
  const int NB1 = (N1 + 1023) / 1024;   // 40
  const int NB2 = (N2 + 1023) / 1024;   // 157

  char* ws = (char*)d_ws;
  __bf16* Z   = (__bf16*)(ws);                 // 51,200,000 B
  float* featA = (float*)(ws + 51200000);      // 20,480,000 B
  float* featB = (float*)(ws + 71680000);      // 20,480,000 B
  float* featC = (float*)(ws + 92160000);      // 10,240,000 B
  float* featD = (float*)(ws + 102400000);     //  5,120,000 B
  int* off    = (int*)(ws + 107520000);        //  640,004 B
  int* cnt    = (int*)(ws + 108170000);        //  640,000 B
  int* eid    = (int*)(ws + 108810000);        //  3,840,000 B
  int* bsum   = (int*)(ws + 112650000);        //  1,024 B
  __bf16* BpA = (__bf16*)(ws + 112660000);     //  40,960 B
  __bf16* BpB = (__bf16*)(ws + 112700960);     //  20,480 B
  __bf16* BpC = (__bf16*)(ws + 112721440);     //  10,240 B
  __bf16* BpD = (__bf16*)(ws + 112731680);     //  10,240 B

  k_pack<64, 32><<<80, 256, 0, stream>>>(W1a, R1a, BpA);
  k_pack<32, 32><<<40, 256, 0, stream>>>(W2a, R2a, BpB);
  k_pack<32, 16><<<20, 256, 0, stream>>>(W1b, R1b, BpC);
  k_pack<16, 16><<<20, 256, 0, stream>>>(W2b, R2b, BpD);

  // ---------------- level 1 ----------------
  k_unpool<<<(N1 * 16 + 255) / 256, 256, 0, stream>>>((const uint4*)x0, up1, (uint4*)featA, N1, 16);

  hipMemsetAsync(cnt, 0, N1 * 4, stream);
  k_hist<<<(E1 + 255) / 256, 256, 0, stream>>>(edge1 + E1, E1, cnt);
  k_blocksum<<<NB1, 256, 0, stream>>>(cnt, N1, bsum);
  k_scanb<<<1, 1024, 0, stream>>>(bsum, NB1);
  k_offsets<<<NB1, 256, 0, stream>>>(cnt, N1, bsum, off, E1);
  hipMemsetAsync(cnt, 0, N1 * 4, stream);
  k_place<<<(E1 + 255) / 256, 256, 0, stream>>>(edge1 + E1, E1, off, cnt, eid);

  // conv1a: x1(64) -> xcat1[:, :32]   (LPD=4: N1*4 threads)
  k_zgemm<64, 320><<<N1 / 64, 256, 0, stream>>>(featA, BpA, Z, N1);
  k_econv<32><<<(N1 * 4 + 255) / 256, 256, 0, stream>>>(edge1, pseudo1, off, eid, Z, b1a, featB, N1, 64);
  k_skip<<<(N1 * 8 + 255) / 256, 256, 0, stream>>>((const uint4*)skip1, (uint4*)featB, N1, 8, 16, 8);
  // conv2a: xcat1(64) -> x3(32)
  k_zgemm<64, 320><<<N1 / 64, 256, 0, stream>>>(featB, BpA, Z, N1);
  k_econv<32><<<(N1 * 4 + 255) / 256, 256, 0, stream>>>(edge1, pseudo1, off, eid, Z, b1a, featC, N1, 32);
  // conv3a: x3(32) -> h1(32)
  k_zgemm<32, 320><<<N1 / 64, 256, 0, stream>>>(featC, BpB, Z, N1);
  k_econv<32><<<(N1 * 4 + 255) / 256, 256, 0, stream>>>(edge1, pseudo1, off, eid, Z, b2a, featD, N1, 32);

  // ---------------- level 2 ----------------
  k_unpool<<<(N2 * 8 + 255) / 256, 256, 0, stream>>>((const uint4*)featD, up2, (uint4*)featA, N2, 8);

  hipMemsetAsync(cnt, 0, N2 * 4, stream);
  k_hist<<<(E2 + 255) / 256, 256, 0, stream>>>(edge2 + E2, E2, cnt);
  k_blocksum<<<NB2, 256, 0, stream>>>(cnt, N2, bsum);
  k_scanb<<<1, 1024, 0, stream>>>(bsum, NB2);
  k_offsets<<<NB2, 256, 0, stream>>>(cnt, N2, bsum, off, E2);
  hipMemsetAsync(cnt, 0, N2 * 4, stream);
  k_place<<<(E2 + 255) / 256, 256, 0, stream>>>(edge2 + E2, E2, off, cnt, eid);

  // conv1b: x2(32) -> xcat2[:, :16]   (LPD=2: N2*2 threads)
  k_zgemm<32, 160><<<N2 / 64, 256, 0, stream>>>(featA, BpC, Z, N2);
  k_econv<16><<<(N2 * 2 + 255) / 256, 256, 0, stream>>>(edge2, pseudo2, off, eid, Z, b1b, featB, N2, 32);
  k_skip<<<(N2 * 4 + 255) / 256, 256, 0, stream>>>((const uint4*)skip2, (uint4*)featB, N2, 4, 8, 4);
  // conv2b: xcat2(32) -> x6(16)
  k_zgemm<32, 160><<<N2 / 64, 256, 0, stream>>>(featB, BpC, Z, N2);
  k_econv<16><<<(N2 * 2 + 255) / 256, 256, 0, stream>>>(edge2, pseudo2, off, eid, Z, b1b, featC, N2, 16);
  // conv3b: x6(16) -> out(16)
  k_zgemm<16, 160><<<N2 / 64, 256, 0, stream>>>(featC, BpD, Z, N2);
  k_econv<16><<<(N2 * 2 + 255) / 256, 256, 0, stream>>>(edge2, pseudo2, off, eid, Z, b2b, (float*)d_out, N2, 16);
}

// Round 5
// 467.369 us; speedup vs baseline: 1.6121x; 1.6121x over previous
//
#include <hip/hip_runtime.h>
#include <stdint.h>

typedef __bf16 bf16x8 __attribute__((ext_vector_type(8)));
typedef __bf16 bf16x4 __attribute__((ext_vector_type(4)));
typedef float  f32x4  __attribute__((ext_vector_type(4)));

// ---------------- unpool / skip-concat (all feats stored bf16) ----------------
// fp32 rows -> bf16 rows, gathered
__global__ void k_up_f2b(const float4* __restrict__ xin, const int* __restrict__ up,
                         __bf16* __restrict__ xout, int N, int rowF4, int rowC) {
  int i = blockIdx.x * 256 + threadIdx.x;
  if (i >= N * rowF4) return;
  int n = i / rowF4, j = i - n * rowF4;
  float4 v = xin[(size_t)up[n] * rowF4 + j];
  bf16x4 o = {(__bf16)v.x, (__bf16)v.y, (__bf16)v.z, (__bf16)v.w};
  *reinterpret_cast<bf16x4*>(xout + (size_t)n * rowC + j * 4) = o;
}

// bf16 rows gathered (uint4 = 8 bf16)
__global__ void k_up_b2b(const uint4* __restrict__ xin, const int* __restrict__ up,
                         uint4* __restrict__ xout, int N, int rowU4) {
  int i = blockIdx.x * 256 + threadIdx.x;
  if (i >= N * rowU4) return;
  int n = i / rowU4, j = i - n * rowU4;
  xout[i] = xin[(size_t)up[n] * rowU4 + j];
}

// fp32 skip -> bf16 columns of concat buffer
__global__ void k_skipcvt(const float4* __restrict__ skip, __bf16* __restrict__ xcat,
                          int N, int rowF4, int dstStride, int dstOff) {
  int i = blockIdx.x * 256 + threadIdx.x;
  if (i >= N * rowF4) return;
  int n = i / rowF4, j = i - n * rowF4;
  float4 v = skip[i];
  bf16x4 o = {(__bf16)v.x, (__bf16)v.y, (__bf16)v.z, (__bf16)v.w};
  *reinterpret_cast<bf16x4*>(xcat + (size_t)n * dstStride + dstOff + j * 4) = o;
}

// ---------------- CSR build ----------------
__global__ void k_hist(const int* __restrict__ dst, int E, int* __restrict__ cnt) {
  int e = blockIdx.x * 256 + threadIdx.x;
  if (e < E) atomicAdd(&cnt[dst[e]], 1);
}

__global__ void k_blocksum(const int* __restrict__ cnt, int N, int* __restrict__ bsum) {
  int b = blockIdx.x;
  int t = threadIdx.x;
  int i0 = b * 1024 + t * 4;
  int s = 0;
  if (i0 + 3 < N) {
    int4 v = *reinterpret_cast<const int4*>(cnt + i0);
    s = v.x + v.y + v.z + v.w;
  } else {
    #pragma unroll
    for (int k = 0; k < 4; ++k) if (i0 + k < N) s += cnt[i0 + k];
  }
  #pragma unroll
  for (int o = 32; o > 0; o >>= 1) s += __shfl_down(s, o, 64);
  __shared__ int ws[4];
  if ((t & 63) == 0) ws[t >> 6] = s;
  __syncthreads();
  if (t == 0) bsum[b] = ws[0] + ws[1] + ws[2] + ws[3];
}

__global__ void k_scanb(int* __restrict__ bsum, int nb) {
  __shared__ int wsum[16];
  int t = threadIdx.x, lane = t & 63, w = t >> 6;
  int v = (t < nb) ? bsum[t] : 0;
  int x = v;
  #pragma unroll
  for (int o = 1; o < 64; o <<= 1) { int y = __shfl_up(x, o, 64); if (lane >= o) x += y; }
  if (lane == 63) wsum[w] = x;
  __syncthreads();
  int wpre = 0;
  #pragma unroll
  for (int k = 0; k < 16; ++k) if (k < w) wpre += wsum[k];
  int excl = wpre + x - v;
  if (t < nb) bsum[t] = excl;
}

__global__ void k_offsets(const int* __restrict__ cnt, int N, const int* __restrict__ bsum,
                          int* __restrict__ off, int E) {
  int b = blockIdx.x;
  int t = threadIdx.x, lane = t & 63, w = t >> 6;
  int i0 = b * 1024 + t * 4;
  int v0 = 0, v1 = 0, v2 = 0, v3 = 0;
  if (i0 + 3 < N) {
    int4 v = *reinterpret_cast<const int4*>(cnt + i0);
    v0 = v.x; v1 = v.y; v2 = v.z; v3 = v.w;
  } else {
    if (i0 + 0 < N) v0 = cnt[i0 + 0];
    if (i0 + 1 < N) v1 = cnt[i0 + 1];
    if (i0 + 2 < N) v2 = cnt[i0 + 2];
    if (i0 + 3 < N) v3 = cnt[i0 + 3];
  }
  int s = v0 + v1 + v2 + v3, x = s;
  #pragma unroll
  for (int o = 1; o < 64; o <<= 1) { int y = __shfl_up(x, o, 64); if (lane >= o) x += y; }
  __shared__ int ws[4];
  if (lane == 63) ws[w] = x;
  __syncthreads();
  int wpre = 0;
  #pragma unroll
  for (int k = 0; k < 4; ++k) if (k < w) wpre += ws[k];
  int excl = bsum[b] + wpre + x - s;
  if (i0 + 0 < N) off[i0 + 0] = excl; excl += v0;
  if (i0 + 1 < N) off[i0 + 1] = excl; excl += v1;
  if (i0 + 2 < N) off[i0 + 2] = excl; excl += v2;
  if (i0 + 3 < N) off[i0 + 3] = excl;
  if (b == 0 && t == 0) off[N] = E;
}

// place edges in CSR order AND pre-gather src + pseudo into CSR order,
// so the conv kernels read them streaming.
__global__ void k_place(const int* __restrict__ src, const int* __restrict__ dst,
                        const float2* __restrict__ pse, int E,
                        const int* __restrict__ off, int* __restrict__ cur,
                        int* __restrict__ srcC, float2* __restrict__ pseC) {
  int e = blockIdx.x * 256 + threadIdx.x;
  if (e >= E) return;
  int d = dst[e];
  int p = atomicAdd(&cur[d], 1);
  int pos = off[d] + p;
  srcC[pos] = src[e];
  pseC[pos] = pse[e];
}

// ---------------- pack [W;R] -> bf16 MFMA B-fragments, B2[K=10*Cin][Cout] --------------
// rows k<9*Cin: W[k9=k/Cin][cin=k%Cin][cout]; rows k>=9*Cin: R[k-9*Cin][cout].
// Bp element o = ((kc*CT+ct)*64 + lane)*8 + j holds B2[kc*32+(lane>>4)*8+j][ct*16+(lane&15)]
template<int Cin, int Cout>
__global__ void k_pack(const float* __restrict__ W, const float* __restrict__ R,
                       __bf16* __restrict__ Bp) {
  constexpr int K = 10 * Cin;
  constexpr int CT = Cout / 16;
  int o = blockIdx.x * 256 + threadIdx.x;
  if (o >= K * Cout) return;
  int j = o & 7;
  int lane = (o >> 3) & 63;
  int tile = o >> 9;
  int ct = tile % CT, kc = tile / CT;
  int k = kc * 32 + ((lane >> 4) * 8) + j;
  int n = ct * 16 + (lane & 15);
  float v;
  if (k < 9 * Cin) {
    int k9 = k / Cin, cin = k - k9 * Cin;
    v = W[(k9 * Cin + cin) * Cout + n];
  } else {
    v = R[(k - 9 * Cin) * Cout + n];
  }
  Bp[o] = (__bf16)v;
}

// -------- fused spline conv: X-space gather-accumulate (A9 in regs) -> LDS -> MFMA -----
// thread group of LPD=Cin/8 lanes owns one dst; each lane owns an 8-wide cin slice.
// A_ext[d] = [ A9[d] (9*Cin) | x_d (Cin) ], contracted with packed [W;R] (K=10*Cin).
template<int Cin, int Cout, bool OUTF32>
__global__ __launch_bounds__(256) void k_conv(const int* __restrict__ off,
                        const int* __restrict__ srcC, const float2* __restrict__ pseC,
                        const __bf16* __restrict__ X, const __bf16* __restrict__ Bp,
                        const float* __restrict__ bias, void* __restrict__ outv,
                        int N, int outStride) {
  constexpr int LPD = Cin / 8;      // lanes per dst: 2/4/8
  constexpr int DPB = 256 / LPD;    // dsts per block: 128/64/32
  constexpr int K   = 10 * Cin;     // 160/320/640
  constexpr int KP2 = K + 8;        // LDS row stride (16B-aligned, breaks pow2 banks)
  constexpr int NT  = DPB / 16;     // MFMA tiles per block: 8/4/2
  constexpr int KC  = K / 32;       // 5/10/20
  constexpr int CT  = Cout / 16;    // 1/2

  __shared__ __bf16 As[DPB * KP2];

  int t = threadIdx.x;
  int g = t / LPD, sub = t % LPD;
  int d = blockIdx.x * DPB + g;

  float acc[9][8];
  #pragma unroll
  for (int k = 0; k < 9; ++k)
    #pragma unroll
    for (int v = 0; v < 8; ++v) acc[k][v] = 0.f;
  bf16x8 xd = {};

  if (d < N) {
    xd = *reinterpret_cast<const bf16x8*>(X + (size_t)d * Cin + sub * 8);
    int b0 = off[d], b1 = off[d + 1];
    for (int i = b0; i < b1; ++i) {
      int s = srcC[i];
      float2 ps = pseC[i];
      bf16x8 xf = *reinterpret_cast<const bf16x8*>(X + (size_t)s * Cin + sub * 8);
      float t0 = ps.x, t1 = ps.y;
      float u0 = 1.f - t0;
      float wi[3] = {0.5f * u0 * u0, -t0 * t0 + t0 + 0.5f, 0.5f * t0 * t0};
      float u1 = 1.f - t1;
      float wj[3] = {0.5f * u1 * u1, -t1 * t1 + t1 + 0.5f, 0.5f * t1 * t1};
      float xfv[8];
      #pragma unroll
      for (int v = 0; v < 8; ++v) xfv[v] = (float)xf[v];
      #pragma unroll
      for (int ki = 0; ki < 3; ++ki)
        #pragma unroll
        for (int kj = 0; kj < 3; ++kj) {
          float w = wi[ki] * wj[kj];
          #pragma unroll
          for (int v = 0; v < 8; ++v)
            acc[ki * 3 + kj][v] += w * xfv[v];
        }
    }
  }

  // stage A_ext row into LDS (bf16)
  __bf16* row = As + (size_t)g * KP2;
  #pragma unroll
  for (int k = 0; k < 9; ++k) {
    bf16x8 tmp;
    #pragma unroll
    for (int v = 0; v < 8; ++v) tmp[v] = (__bf16)acc[k][v];
    *reinterpret_cast<bf16x8*>(row + k * Cin + sub * 8) = tmp;
  }
  *reinterpret_cast<bf16x8*>(row + 9 * Cin + sub * 8) = xd;
  __syncthreads();

  // MFMA: tiles of 16 dsts
  int lane = t & 63, wave = t >> 6;
  int c15 = lane & 15, q = lane >> 4;
  for (int tile = wave; tile < NT; tile += 4) {
    const __bf16* arow = As + (size_t)(tile * 16 + c15) * KP2 + q * 8;
    #pragma unroll
    for (int ct = 0; ct < CT; ++ct) {
      f32x4 a4 = {0.f, 0.f, 0.f, 0.f};
      #pragma unroll
      for (int kc = 0; kc < KC; ++kc) {
        bf16x8 a = *reinterpret_cast<const bf16x8*>(arow + kc * 32);
        bf16x8 b = *reinterpret_cast<const bf16x8*>(Bp + ((size_t)(kc * CT + ct) * 64 + lane) * 8);
        a4 = __builtin_amdgcn_mfma_f32_16x16x32_bf16(a, b, a4, 0, 0, 0);
      }
      int cout = ct * 16 + c15;
      float bb = bias[cout];
      #pragma unroll
      for (int r = 0; r < 4; ++r) {
        int m = q * 4 + r;
        int dd = blockIdx.x * DPB + tile * 16 + m;
        if (dd < N) {
          float vv = fmaxf(a4[r] + bb, 0.f);
          if constexpr (OUTF32)
            ((float*)outv)[(size_t)dd * outStride + cout] = vv;
          else
            ((__bf16*)outv)[(size_t)dd * outStride + cout] = (__bf16)vv;
        }
      }
    }
  }
}

extern "C" void kernel_launch(void* const* d_in, const int* in_sizes, int n_in,
                              void* d_out, int out_size, void* d_ws, size_t ws_size,
                              hipStream_t stream) {
  const float* x0      = (const float*)d_in[0];
  const int*   up1     = (const int*)d_in[1];
  const int*   edge1   = (const int*)d_in[2];
  const float* pseudo1 = (const float*)d_in[3];
  const float* skip1   = (const float*)d_in[4];
  const int*   up2     = (const int*)d_in[5];
  const int*   edge2   = (const int*)d_in[6];
  const float* pseudo2 = (const float*)d_in[7];
  const float* skip2   = (const float*)d_in[8];
  const float* W1a = (const float*)d_in[9];
  const float* R1a = (const float*)d_in[10];
  const float* b1a = (const float*)d_in[11];
  const float* W2a = (const float*)d_in[12];
  const float* R2a = (const float*)d_in[13];
  const float* b2a = (const float*)d_in[14];
  const float* W1b = (const float*)d_in[15];
  const float* R1b = (const float*)d_in[16];
  const float* b1b = (const float*)d_in[17];
  const float* W2b = (const float*)d_in[18];
  const float* R2b = (const float*)d_in[19];
  const float* b2b = (const float*)d_in[20];

  const int N1 = 40000, N2 = 160000, E1 = 240000, E2 = 960000;
  const int NB1 = (N1 + 1023) / 1024;   // 40
  const int NB2 = (N2 + 1023) / 1024;   // 157

  char* ws = (char*)d_ws;
  __bf16* x1    = (__bf16*)(ws);               // [N1,64]  5,120,000 B
  __bf16* xcat1 = (__bf16*)(ws +  5120000);    // [N1,64]  5,120,000
  __bf16* x3    = (__bf16*)(ws + 10240000);    // [N1,32]  2,560,000
  __bf16* h1    = (__bf16*)(ws + 12800000);    // [N1,32]  2,560,000
  __bf16* x2    = (__bf16*)(ws + 15360000);    // [N2,32] 10,240,000
  __bf16* xcat2 = (__bf16*)(ws + 25600000);    // [N2,32] 10,240,000
  __bf16* x6    = (__bf16*)(ws + 35840000);    // [N2,16]  5,120,000
  int* off    = (int*)(ws + 40960000);         // (N2+1)*4
  int* cnt    = (int*)(ws + 41600016);         // N2*4
  int* srcC   = (int*)(ws + 42240016);         // E2*4
  float2* pseC = (float2*)(ws + 46080016);     // E2*8
  int* bsum   = (int*)(ws + 53760016);         // 1 KB
  __bf16* BpA = (__bf16*)(ws + 53761040);      // 640*32*2 = 40,960
  __bf16* BpB = (__bf16*)(ws + 53802000);      // 320*32*2 = 20,480
  __bf16* BpC = (__bf16*)(ws + 53822480);      // 320*16*2 = 10,240
  __bf16* BpD = (__bf16*)(ws + 53832720);      // 160*16*2 =  5,120

  // weight packs (tiny)
  k_pack<64, 32><<<80, 256, 0, stream>>>(W1a, R1a, BpA);
  k_pack<32, 32><<<40, 256, 0, stream>>>(W2a, R2a, BpB);
  k_pack<32, 16><<<20, 256, 0, stream>>>(W1b, R1b, BpC);
  k_pack<16, 16><<<10, 256, 0, stream>>>(W2b, R2b, BpD);

  // ---------------- level 1 ----------------
  k_up_f2b<<<N1 * 16 / 256, 256, 0, stream>>>((const float4*)x0, up1, x1, N1, 16, 64);

  hipMemsetAsync(cnt, 0, N1 * 4, stream);
  k_hist<<<(E1 + 255) / 256, 256, 0, stream>>>(edge1 + E1, E1, cnt);
  k_blocksum<<<NB1, 256, 0, stream>>>(cnt, N1, bsum);
  k_scanb<<<1, 1024, 0, stream>>>(bsum, NB1);
  k_offsets<<<NB1, 256, 0, stream>>>(cnt, N1, bsum, off, E1);
  hipMemsetAsync(cnt, 0, N1 * 4, stream);
  k_place<<<(E1 + 255) / 256, 256, 0, stream>>>(edge1, edge1 + E1, (const float2*)pseudo1,
                                                E1, off, cnt, srcC, pseC);

  // conv1a: x1(64) -> xcat1[:, :32]
  k_conv<64, 32, false><<<N1 / 32, 256, 0, stream>>>(off, srcC, pseC, x1, BpA, b1a, xcat1, N1, 64);
  k_skipcvt<<<N1 * 8 / 256, 256, 0, stream>>>((const float4*)skip1, xcat1, N1, 8, 64, 32);
  // conv2a (reuses W1a,R1a,b1a): xcat1(64) -> x3(32)
  k_conv<64, 32, false><<<N1 / 32, 256, 0, stream>>>(off, srcC, pseC, xcat1, BpA, b1a, x3, N1, 32);
  // conv3a: x3(32) -> h1(32)
  k_conv<32, 32, false><<<N1 / 64, 256, 0, stream>>>(off, srcC, pseC, x3, BpB, b2a, h1, N1, 32);

  // ---------------- level 2 ----------------
  k_up_b2b<<<N2 * 4 / 256, 256, 0, stream>>>((const uint4*)h1, up2, (uint4*)x2, N2, 4);

  hipMemsetAsync(cnt, 0, N2 * 4, stream);
  k_hist<<<(E2 + 255) / 256, 256, 0, stream>>>(edge2 + E2, E2, cnt);
  k_blocksum<<<NB2, 256, 0, stream>>>(cnt, N2, bsum);
  k_scanb<<<1, 1024, 0, stream>>>(bsum, NB2);
  k_offsets<<<NB2, 256, 0, stream>>>(cnt, N2, bsum, off, E2);
  hipMemsetAsync(cnt, 0, N2 * 4, stream);
  k_place<<<(E2 + 255) / 256, 256, 0, stream>>>(edge2, edge2 + E2, (const float2*)pseudo2,
                                                E2, off, cnt, srcC, pseC);

  // conv1b: x2(32) -> xcat2[:, :16]
  k_conv<32, 16, false><<<N2 / 64, 256, 0, stream>>>(off, srcC, pseC, x2, BpC, b1b, xcat2, N2, 32);
  k_skipcvt<<<N2 * 4 / 256, 256, 0, stream>>>((const float4*)skip2, xcat2, N2, 4, 32, 16);
  // conv2b (reuses W1b,R1b,b1b): xcat2(32) -> x6(16)
  k_conv<32, 16, false><<<N2 / 64, 256, 0, stream>>>(off, srcC, pseC, xcat2, BpC, b1b, x6, N2, 16);
  // conv3b: x6(16) -> out(16) fp32
  k_conv<16, 16, true><<<N2 / 128, 256, 0, stream>>>(off, srcC, pseC, x6, BpD, b2b, d_out, N2, 16);
}